// Round 10
// baseline (718.282 us; speedup 1.0000x reference)
//
#include <hip/hip_runtime.h>
#include <stdint.h>

#define NN 4096
#define NE 65536
#define LEAKY 0.01f
#define BN_EPS 1e-5f
#define DSTRIDE 96   // padded adjacency stride (mean deg 16, 12+ sigma margin)
#define NREP 8       // bnsum atomic replicas (chain len 4096/8=512)
#define REPSTRIDE 1280

typedef float f32x4 __attribute__((ext_vector_type(4)));
typedef __bf16 bf16x8 __attribute__((ext_vector_type(8)));
typedef unsigned short u16x8 __attribute__((ext_vector_type(8)));
typedef unsigned short u16x4 __attribute__((ext_vector_type(4)));

static __device__ __forceinline__ unsigned short f2bf(float v) {
  unsigned int u = __float_as_uint(v);
  u += 0x7fff + ((u >> 16) & 1);   // RNE; inputs are finite
  return (unsigned short)(u >> 16);
}

static __device__ __forceinline__ f32x4 bf4f(u16x4 v) {
  f32x4 r;
#pragma unroll
  for (int j = 0; j < 4; ++j) r[j] = __uint_as_float(((unsigned)v[j]) << 16);
  return r;
}

typedef __attribute__((address_space(1))) void gvoid;
typedef __attribute__((address_space(3))) void lvoid;

static __device__ __forceinline__ void async16(const void* g, void* l) {
  __builtin_amdgcn_global_load_lds((gvoid*)(uintptr_t)g,
                                   (lvoid*)(uint32_t)(uintptr_t)l, 16, 0, 0);
}

// ======================= setup: W packs + adjacency build ===================
// bf16 GEMM-input layout: within each 64-col K-group, row r's 16B block b is
// stored at block (b + r) & 7 (LDS de-conflict rotation; GEMM unrotates).
// x_in is NOT packed: layer-1 GEMM converts fp32->bf16 in-staging (R3 design).

static __device__ __forceinline__ void pack_w_seg(int lblk, const float* __restrict__ Wl,
                                                  const float* __restrict__ Wr,
                                                  unsigned short* __restrict__ dst,
                                                  int Fout, int Fin, int Kp, int Np) {
  int nb = Kp >> 3;
  int idx = lblk * 256 + threadIdx.x;
  if (idx >= Np * nb) return;
  int row = idx / nb, kb = idx - row * nb;
  int g = kb >> 3, b = kb & 7;
  int dkb = (g << 3) | ((b + row) & 7);
  const float* src = nullptr;
  if (row < Fout)          src = Wl + (size_t)row * Fin;
  else if (row < 2 * Fout) src = Wr + (size_t)(row - Fout) * Fin;
  u16x8 st;
#pragma unroll
  for (int o = 0; o < 8; ++o) {
    int k = kb * 8 + o;
    float v = (src && k < Fin) ? src[k] : 0.f;
    st[o] = f2bf(v);
  }
  *(u16x8*)&dst[(size_t)row * Kp + dkb * 8] = st;
}

#define ADJ_BLK    256   // 65536/256 (first: atomic tail overlaps pack work)
#define PW1_BLK   2660   // 640*1064/256
#define PW2_BLK     60
#define PW3_BLK     24
#define PW4_BLK      8
#define SETUP_BLK (ADJ_BLK + PW1_BLK + PW2_BLK + PW3_BLK + PW4_BLK)

__global__ __launch_bounds__(256) void setup_all(
    const int* __restrict__ esrc, const int* __restrict__ edst,
    const float* __restrict__ W1l, const float* __restrict__ W1r,
    const float* __restrict__ W2l, const float* __restrict__ W2r,
    const float* __restrict__ W3l, const float* __restrict__ W3r,
    const float* __restrict__ W4l, const float* __restrict__ W4r,
    unsigned short* __restrict__ wb1, unsigned short* __restrict__ wb2,
    unsigned short* __restrict__ wb3, unsigned short* __restrict__ wb4,
    int* __restrict__ deg, int* __restrict__ eix) {
  int blk = blockIdx.x;
  if (blk < ADJ_BLK) {
    // padded-adjacency build: deg pre-zeroed by memset before this kernel
    int e = blk * 256 + threadIdx.x;
    int d = edst[e];
    int pos = atomicAdd(&deg[d], 1);
    if (pos < DSTRIDE) eix[(size_t)d * DSTRIDE + pos] = esrc[e];
  } else if (blk < ADJ_BLK + PW1_BLK) {
    pack_w_seg(blk - ADJ_BLK, W1l, W1r, wb1, 320, 8500, 8512, 640);
  } else if (blk < ADJ_BLK + PW1_BLK + PW2_BLK) {
    pack_w_seg(blk - ADJ_BLK - PW1_BLK, W2l, W2r, wb2, 180, 320, 320, 384);
  } else if (blk < ADJ_BLK + PW1_BLK + PW2_BLK + PW3_BLK) {
    pack_w_seg(blk - ADJ_BLK - PW1_BLK - PW2_BLK, W3l, W3r, wb3, 90, 180, 192, 256);
  } else {
    pack_w_seg(blk - ADJ_BLK - PW1_BLK - PW2_BLK - PW3_BLK, W4l, W4r, wb4,
               50, 90, 128, 128);
  }
}

// ======= layer-1 GEMM (R3-proven): A = x_in fp32, cvt in staging ============
// C = A[M,8500->8512] @ B[N,8512]^T, K-split partials over blockIdx.z (nz=8).
__global__ __launch_bounds__(256) void gemm_f32a(const float* __restrict__ X,
                                                 const unsigned short* __restrict__ B,
                                                 float* __restrict__ C, int N, int M) {
  const int K = 8512, KS = 133, FIN = 8500;
  __shared__ unsigned short smem[3 * 128 * 64];   // As + Bs[2] = 48 KB
  unsigned short* As = smem;

  const int t = threadIdx.x;
  const int bm = blockIdx.x, bn = blockIdx.y;
  const int lane = t & 63;
  const int wave = t >> 6;
  const int wm = (wave & 1) * 64, wn = (wave >> 1) * 64;
  const int l16 = lane & 15, quad = lane >> 4;

  const int gz = (int)gridDim.z, z = (int)blockIdx.z;
  const int per = KS / gz, rem = KS % gz;
  const int k0 = z * per + (z < rem ? z : rem);
  const int k1 = k0 + per + (z < rem ? 1 : 0);

  f32x4 acc[4][4];
#pragma unroll
  for (int i = 0; i < 4; ++i)
#pragma unroll
    for (int j = 0; j < 4; ++j) acc[i][j] = (f32x4){0.f, 0.f, 0.f, 0.f};

  const int srow = t >> 3;          // 0..31
  const int bblk = t & 7;           // 16B block within 64-col group
  const int scol = bblk * 8;
  const float* Xb = X + (size_t)(bm * 128) * FIN;
  const unsigned short* Bbase = B + (size_t)(bn * 128) * K + scol;

  float va[4][8];
  auto loadA = [&](int kt) {
    int gc = kt * 64 + scol;
#pragma unroll
    for (int p = 0; p < 4; ++p) {
      const float* ap = Xb + (size_t)(p * 32 + srow) * FIN + gc;
      if (gc + 8 <= FIN) {
        f32x4 a = *(const f32x4*)ap;
        f32x4 b2 = *(const f32x4*)(ap + 4);
#pragma unroll
        for (int o = 0; o < 4; ++o) { va[p][o] = a[o]; va[p][o + 4] = b2[o]; }
      } else {
#pragma unroll
        for (int o = 0; o < 8; ++o) va[p][o] = (gc + o < FIN) ? ap[o] : 0.f;
      }
    }
  };
  auto writeA = [&]() {
#pragma unroll
    for (int p = 0; p < 4; ++p) {
      int row = p * 32 + srow;
      int rot = ((bblk + row) & 7) * 8;
      bf16x8 bv;
#pragma unroll
      for (int o = 0; o < 8; ++o) bv[o] = (__bf16)va[p][o];
      *(bf16x8*)&As[row * 64 + rot] = bv;
    }
  };
  auto stageB = [&](int kt, int bb) {
    unsigned short* Bd = smem + 128 * 64 + bb * 128 * 64;
#pragma unroll
    for (int p = 0; p < 4; ++p) {
      int row = p * 32 + srow;
      async16(Bbase + (size_t)row * K + kt * 64, &Bd[row * 64 + scol]);
    }
  };

  // prologue: stage k0 (A via regs, B async into buf 0)
  loadA(k0);
  stageB(k0, 0);
  writeA();
  __syncthreads();

  int bb = 0;
  for (int kt = k0; kt < k1; ++kt) {
    bool more = (kt + 1 < k1);
    if (more) {
      loadA(kt + 1);            // global loads in flight under MFMA
      stageB(kt + 1, bb ^ 1);   // async into idle B buffer
    }
    const unsigned short* Bs = smem + 128 * 64 + bb * 128 * 64;
#pragma unroll
    for (int kh = 0; kh < 2; ++kh) {
      const int s8 = ((kh * 4 + quad + l16) & 7) * 8;   // unrotate
      bf16x8 af[4], bfr[4];
#pragma unroll
      for (int i = 0; i < 4; ++i)
        af[i] = *(const bf16x8*)&As[(wm + i * 16 + l16) * 64 + s8];
#pragma unroll
      for (int j = 0; j < 4; ++j)
        bfr[j] = *(const bf16x8*)&Bs[(wn + j * 16 + l16) * 64 + s8];
#pragma unroll
      for (int i = 0; i < 4; ++i)
#pragma unroll
        for (int j = 0; j < 4; ++j)
          acc[i][j] = __builtin_amdgcn_mfma_f32_16x16x32_bf16(af[i], bfr[j], acc[i][j], 0, 0, 0);
    }
    __syncthreads();            // compute done; As reusable
    if (more) {
      writeA();                 // cvt + rotated ds_write (waits va loads)
      __syncthreads();          // staging visible
      bb ^= 1;
    }
  }

  float* Cb = C + (size_t)blockIdx.z * M * N;
#pragma unroll
  for (int i = 0; i < 4; ++i) {
    int rbase = bm * 128 + wm + i * 16 + quad * 4;
#pragma unroll
    for (int j = 0; j < 4; ++j) {
      int col = bn * 128 + wn + j * 16 + l16;
      float* cp = Cb + (size_t)rbase * N + col;
#pragma unroll
      for (int r = 0; r < 4; ++r) cp[(size_t)r * N] = acc[i][j][r];
    }
  }
}

// -------- bf16 MFMA GEMM (layers 2-4): C[bf16] = A[M,K] @ B[N,K]^T ----------
__global__ __launch_bounds__(256) void gemm_bt(const unsigned short* __restrict__ A,
                                               const unsigned short* __restrict__ B,
                                               unsigned short* __restrict__ C, int N,
                                               int K, int M) {
  __shared__ unsigned short smem[2 * 128 * 64];
  unsigned short* As = smem;
  unsigned short* Bs = smem + 128 * 64;

  const int t = threadIdx.x;
  const int bm = blockIdx.x, bn = blockIdx.y;
  const int lane = t & 63;
  const int wave = t >> 6;
  const int wm = (wave & 1) * 64, wn = (wave >> 1) * 64;
  const int l16 = lane & 15, quad = lane >> 4;

  const int ksteps = K >> 6;

  f32x4 acc[4][4];
#pragma unroll
  for (int i = 0; i < 4; ++i)
#pragma unroll
    for (int j = 0; j < 4; ++j) acc[i][j] = (f32x4){0.f, 0.f, 0.f, 0.f};

  const int srow = t >> 3;
  const int scol = (t & 7) * 8;
  const unsigned short* Abase = A + (size_t)(bm * 128) * K + scol;
  const unsigned short* Bbase = B + (size_t)(bn * 128) * K + scol;

  for (int kt = 0; kt < ksteps; ++kt) {
    const unsigned short* Ag = Abase + kt * 64;
    const unsigned short* Bg = Bbase + kt * 64;
#pragma unroll
    for (int p = 0; p < 4; ++p) {
      int row = p * 32 + srow;
      async16(Ag + (size_t)row * K, &As[row * 64 + scol]);
    }
#pragma unroll
    for (int p = 0; p < 4; ++p) {
      int row = p * 32 + srow;
      async16(Bg + (size_t)row * K, &Bs[row * 64 + scol]);
    }
    __syncthreads();
#pragma unroll
    for (int kh = 0; kh < 2; ++kh) {
      const int s8 = ((kh * 4 + quad + l16) & 7) * 8;   // unrotate
      bf16x8 af[4], bfr[4];
#pragma unroll
      for (int i = 0; i < 4; ++i)
        af[i] = *(const bf16x8*)&As[(wm + i * 16 + l16) * 64 + s8];
#pragma unroll
      for (int j = 0; j < 4; ++j)
        bfr[j] = *(const bf16x8*)&Bs[(wn + j * 16 + l16) * 64 + s8];
#pragma unroll
      for (int i = 0; i < 4; ++i)
#pragma unroll
        for (int j = 0; j < 4; ++j)
          acc[i][j] = __builtin_amdgcn_mfma_f32_16x16x32_bf16(af[i], bfr[j], acc[i][j], 0, 0, 0);
    }
    __syncthreads();
  }

#pragma unroll
  for (int i = 0; i < 4; ++i) {
    int rbase = bm * 128 + wm + i * 16 + quad * 4;
#pragma unroll
    for (int j = 0; j < 4; ++j) {
      int col = bn * 128 + wn + j * 16 + l16;
      unsigned short* cp = C + (size_t)rbase * N + col;
#pragma unroll
      for (int r = 0; r < 4; ++r) cp[(size_t)r * N] = f2bf(acc[i][j][r]);
    }
  }
}

// sum nz fp32 K-split slabs -> bf16 y; grid exact NN*640/8/256
__global__ void reduceNbf(const float* __restrict__ yp, unsigned short* __restrict__ y,
                          int nz) {
  int idx = blockIdx.x * 256 + threadIdx.x;    // 8 elems per thread
  const f32x4* p = (const f32x4*)yp;
  const int S = NN * 640 / 4;
  int i2 = idx * 2;
  f32x4 a = p[i2], b = p[i2 + 1];
  for (int sl = 1; sl < nz; ++sl) {
    a += p[i2 + (size_t)sl * S];
    b += p[i2 + 1 + (size_t)sl * S];
  }
  u16x8 st;
#pragma unroll
  for (int o = 0; o < 4; ++o) { st[o] = f2bf(a[o]); st[o + 4] = f2bf(b[o]); }
  *(u16x8*)&y[(size_t)idx * 8] = st;
}

// ------- fused mean-aggregate + root + bias + leaky + BN partial sums -------
// y is bf16. block (64,4). At z-write time, atomically accumulate sum/sum^2
// into replica (i & 7) of the layer's bnsum region (chain len 512/addr).
__global__ __launch_bounds__(256) void sage_agg(
    const unsigned short* __restrict__ y, const int* __restrict__ deg,
    const int* __restrict__ eix, const float* __restrict__ bias,
    float* __restrict__ z, float* __restrict__ sums, int F, int ldy) {
  int i = blockIdx.x;
  int tx = threadIdx.x, ty = threadIdx.y;
  __shared__ int se[DSTRIDE];
  __shared__ float red[3][64][4];
  int d = deg[i]; if (d > DSTRIDE) d = DSTRIDE;
  // stage edge list (d <= 96 -> one pass with 256 threads)
  {
    int lt = ty * 64 + tx;
    if (lt < d) se[lt] = eix[(size_t)i * DSTRIDE + lt];
  }
  __syncthreads();
  float* sr = sums + (size_t)(i & (NREP - 1)) * REPSTRIDE;
  int nfb = (F + 255) >> 8;
  for (int fb = 0; fb < nfb; ++fb) {
    int f4 = (fb * 64 + tx) * 4;
    bool active = (f4 < F);
    f32x4 s = {0.f, 0.f, 0.f, 0.f};
    if (active) {
      const unsigned short* yb = y + f4;
      int e = ty;
      for (; e + 4 < d; e += 8) {   // 2x unroll: two independent loads in flight
        u16x4 a = *(const u16x4*)&yb[(size_t)se[e] * ldy];
        u16x4 b = *(const u16x4*)&yb[(size_t)se[e + 4] * ldy];
        s += bf4f(a); s += bf4f(b);
      }
      if (e < d) s += bf4f(*(const u16x4*)&yb[(size_t)se[e] * ldy]);
    }
    if (ty > 0) *(f32x4*)red[ty - 1][tx] = s;
    __syncthreads();
    if (ty == 0 && active) {
      s += *(const f32x4*)red[0][tx];
      s += *(const f32x4*)red[1][tx];
      s += *(const f32x4*)red[2][tx];
      float inv = 1.f / (float)(d > 1 ? d : 1);
      int cnt = F - f4; if (cnt > 4) cnt = 4;
      const unsigned short* yr = &y[(size_t)i * ldy + F + f4];
      float* zo = &z[(size_t)i * F + f4];
      for (int j = 0; j < cnt; ++j) {
        float rv = __uint_as_float(((unsigned)yr[j]) << 16);
        float w = s[j] * inv + rv + bias[f4 + j];
        w = (w >= 0.f) ? w : LEAKY * w;
        zo[j] = w;
        atomicAdd(&sr[f4 + j], w);
        atomicAdd(&sr[F + f4 + j], w * w);
      }
    }
    if (fb + 1 < nfb) __syncthreads();   // red reuse barrier
  }
}

// normalize -> next layer's rotated bf16 input. Sums the NREP bnsum replicas
// once per block into LDS (m, rs per feature), then packs.
__global__ void bn_norm8(const float* __restrict__ z, const float* __restrict__ sums,
                         unsigned short* __restrict__ xout, int F, int Kp) {
  __shared__ float ms[320], rss[320];
  for (int k = threadIdx.x; k < F; k += 256) {
    float sm = 0.f, sq = 0.f;
#pragma unroll
    for (int r = 0; r < NREP; ++r) {
      sm += sums[(size_t)r * REPSTRIDE + k];
      sq += sums[(size_t)r * REPSTRIDE + F + k];
    }
    float m = sm * (1.f / NN);
    float var = sq * (1.f / NN) - m * m;
    ms[k] = m;
    rss[k] = rsqrtf(var + BN_EPS);
  }
  __syncthreads();
  int nb = Kp >> 3;
  int idx = blockIdx.x * 256 + threadIdx.x;    // exact grid
  int row = idx / nb, kb = idx - row * nb;
  int g = kb >> 3, b = kb & 7;
  int dkb = (g << 3) | ((b + row) & 7);
  u16x8 st;
#pragma unroll
  for (int o = 0; o < 8; ++o) {
    int k = kb * 8 + o;
    float v = 0.f;
    if (k < F) v = (z[(size_t)row * F + k] - ms[k]) * rss[k];
    st[o] = f2bf(v);
  }
  *(u16x8*)&xout[(size_t)row * Kp + dkb * 8] = st;
}

// ---------------- pool (BN folded in, replica sums) + 3 FC layers ----------
// block (64,4): ty stripes the 256 rows of each batch segment.
__global__ void pool_fc(const float* __restrict__ z,  // [4096, 50] pre-BN
                        const float* __restrict__ sums,
                        const float* __restrict__ Wf1, const float* __restrict__ bf1,
                        const float* __restrict__ Wf2, const float* __restrict__ bf2,
                        const float* __restrict__ Wf3, const float* __restrict__ bf3,
                        float* __restrict__ out) {
  __shared__ float ps[4][50];
  __shared__ float pool[50];
  __shared__ float h1[32], h2[16];
  int b = blockIdx.x, tx = threadIdx.x, ty = threadIdx.y;
  if (tx < 50) {
    float s = 0.f;
    int r0 = b * 256 + ty * 64;
    for (int r = 0; r < 64; ++r) s += z[(size_t)(r0 + r) * 50 + tx];
    ps[ty][tx] = s;
  }
  __syncthreads();
  if (ty == 0 && tx < 50) {
    float s = ps[0][tx] + ps[1][tx] + ps[2][tx] + ps[3][tx];
    float sm = 0.f, sq = 0.f;
#pragma unroll
    for (int r = 0; r < NREP; ++r) {
      sm += sums[(size_t)r * REPSTRIDE + tx];
      sq += sums[(size_t)r * REPSTRIDE + 50 + tx];
    }
    float m  = sm * (1.f / NN);
    float var = sq * (1.f / NN) - m * m;
    float rs = rsqrtf(var + BN_EPS);
    pool[tx] = (s - 256.f * m) * rs;   // sum of normalized = (sum - n*m)*rs
  }
  __syncthreads();
  if (ty == 0 && tx < 32) {
    float s = bf1[tx];
    for (int f = 0; f < 50; ++f) s += pool[f] * Wf1[tx * 50 + f];
    h1[tx] = s;
  }
  __syncthreads();
  if (ty == 0 && tx < 16) {
    float s = bf2[tx];
    for (int f = 0; f < 32; ++f) s += h1[f] * Wf2[tx * 32 + f];
    h2[tx] = s;
  }
  __syncthreads();
  if (ty == 0 && tx == 0) {
    float s = bf3[0];
    for (int f = 0; f < 16; ++f) s += h2[f] * Wf3[f];
    out[b] = s;
  }
}

// ---------------- host ----------------

extern "C" void kernel_launch(void* const* d_in, const int* in_sizes, int n_in,
                              void* d_out, int out_size, void* d_ws, size_t ws_size,
                              hipStream_t stream) {
  const float* x_in = (const float*)d_in[0];
  const int* ei = (const int*)d_in[1];      // int32 per harness contract
  const float* W1l = (const float*)d_in[2];
  const float* b1  = (const float*)d_in[3];
  const float* W1r = (const float*)d_in[4];
  const float* W2l = (const float*)d_in[5];
  const float* b2  = (const float*)d_in[6];
  const float* W2r = (const float*)d_in[7];
  const float* W3l = (const float*)d_in[8];
  const float* b3  = (const float*)d_in[9];
  const float* W3r = (const float*)d_in[10];
  const float* W4l = (const float*)d_in[11];
  const float* b4  = (const float*)d_in[12];
  const float* W4r = (const float*)d_in[13];
  const float* Wf1 = (const float*)d_in[14];
  const float* bf1 = (const float*)d_in[15];
  const float* Wf2 = (const float*)d_in[16];
  const float* bf2 = (const float*)d_in[17];
  const float* Wf3 = (const float*)d_in[18];
  const float* bf3 = (const float*)d_in[19];
  float* out = (float*)d_out;
  (void)in_sizes; (void)n_in; (void)out_size;

  char* ws = (char*)d_ws;
  size_t off = 0;
  auto alloc = [&](size_t bytes) -> void* {
    void* p = ws + off;
    off = (off + bytes + 255) & ~(size_t)255;
    return p;
  };
  unsigned short* xbf = (unsigned short*)alloc((size_t)NN * 320 * 2);  // layers 2-4 A
  unsigned short* wb1 = (unsigned short*)alloc((size_t)640 * 8512 * 2);
  unsigned short* wb2 = (unsigned short*)alloc((size_t)384 * 320 * 2);
  unsigned short* wb3 = (unsigned short*)alloc((size_t)256 * 192 * 2);
  unsigned short* wb4 = (unsigned short*)alloc((size_t)128 * 128 * 2);
  float* z    = (float*)alloc((size_t)NN * 320 * 4);
  // contiguous zero region: deg + bnsum replicas
  int* deg    = (int*)alloc(NN * 4);
  float* bnsum = (float*)alloc((size_t)NREP * REPSTRIDE * 4);
  int* eix    = (int*)alloc((size_t)NN * DSTRIDE * 4);
  unsigned short* ybf = (unsigned short*)alloc((size_t)NN * 640 * 2);  // bf16 y
  const size_t YS = (size_t)NN * 640 * 4;   // one fp32 K-split slab
  float* yp = (float*)(ws + off);           // partial slabs last
  int nz = (off + 8 * YS <= ws_size) ? 8 : 4;
  if (off + (size_t)nz * YS > ws_size) return;
  float* bns1 = bnsum;             // replica-0 base per layer (stride REPSTRIDE)
  float* bns2 = bnsum + 640;       // 2*180
  float* bns3 = bnsum + 1000;      // 2*90
  float* bns4 = bnsum + 1180;      // 2*50

  hipMemsetAsync(deg, 0, NN * 4 + (size_t)NREP * REPSTRIDE * 4, stream);

  setup_all<<<dim3(SETUP_BLK), dim3(256), 0, stream>>>(
      ei, ei + NE, W1l, W1r, W2l, W2r, W3l, W3r, W4l, W4r,
      wb1, wb2, wb3, wb4, deg, eix);

  // ---- layer 1: K=8512 (fp32 A in-staging cvt), K-split nz=8 + bf16 reduce ----
  gemm_f32a<<<dim3(32, 5, nz), dim3(256), 0, stream>>>(x_in, wb1, yp, 640, NN);
  reduceNbf<<<dim3(NN * 640 / 8 / 256), dim3(256), 0, stream>>>(yp, ybf, nz);
  sage_agg<<<dim3(NN), dim3(64, 4), 0, stream>>>(ybf, deg, eix, b1, z, bns1, 320, 640);
  bn_norm8<<<dim3(NN * 40 / 256), dim3(256), 0, stream>>>(z, bns1, xbf, 320, 320);

  // ---- layer 2: K=320, N=384 ----
  gemm_bt<<<dim3(32, 3, 1), dim3(256), 0, stream>>>(xbf, wb2, ybf, 384, 320, NN);
  sage_agg<<<dim3(NN), dim3(64, 4), 0, stream>>>(ybf, deg, eix, b2, z, bns2, 180, 384);
  bn_norm8<<<dim3(NN * 24 / 256), dim3(256), 0, stream>>>(z, bns2, xbf, 180, 192);

  // ---- layer 3: K=192, N=256 ----
  gemm_bt<<<dim3(32, 2, 1), dim3(256), 0, stream>>>(xbf, wb3, ybf, 256, 192, NN);
  sage_agg<<<dim3(NN), dim3(64, 4), 0, stream>>>(ybf, deg, eix, b3, z, bns3, 90, 256);
  bn_norm8<<<dim3(NN * 16 / 256), dim3(256), 0, stream>>>(z, bns3, xbf, 90, 128);

  // ---- layer 4: K=128, N=128 ----
  gemm_bt<<<dim3(32, 1, 1), dim3(256), 0, stream>>>(xbf, wb4, ybf, 128, 128, NN);
  sage_agg<<<dim3(NN), dim3(64, 4), 0, stream>>>(ybf, deg, eix, b4, z, bns4, 50, 128);

  // ---- pool (BN folded, replica sums) + FC ----
  pool_fc<<<dim3(16), dim3(64, 4), 0, stream>>>(z, bns4, Wf1, bf1, Wf2, bf2, Wf3, bf3, out);
}

// Round 11
// 477.135 us; speedup vs baseline: 1.5054x; 1.5054x over previous
//
#include <hip/hip_runtime.h>
#include <stdint.h>

#define NN 4096
#define NE 65536
#define LEAKY 0.01f
#define BN_EPS 1e-5f
#define DSTRIDE 96   // padded adjacency stride (mean deg 16, 12+ sigma margin)

typedef float f32x4 __attribute__((ext_vector_type(4)));
typedef __bf16 bf16x8 __attribute__((ext_vector_type(8)));
typedef unsigned short u16x8 __attribute__((ext_vector_type(8)));
typedef unsigned short u16x4 __attribute__((ext_vector_type(4)));

static __device__ __forceinline__ unsigned short f2bf(float v) {
  unsigned int u = __float_as_uint(v);
  u += 0x7fff + ((u >> 16) & 1);   // RNE; inputs are finite
  return (unsigned short)(u >> 16);
}

static __device__ __forceinline__ f32x4 bf4f(u16x4 v) {
  f32x4 r;
#pragma unroll
  for (int j = 0; j < 4; ++j) r[j] = __uint_as_float(((unsigned)v[j]) << 16);
  return r;
}

typedef __attribute__((address_space(1))) void gvoid;
typedef __attribute__((address_space(3))) void lvoid;

static __device__ __forceinline__ void async16(const void* g, void* l) {
  __builtin_amdgcn_global_load_lds((gvoid*)(uintptr_t)g,
                                   (lvoid*)(uint32_t)(uintptr_t)l, 16, 0, 0);
}

// ======================= setup: W packs + adjacency build ===================
// bf16 GEMM-input layout: within each 64-col K-group, row r's 16B block b is
// stored at block (b + r) & 7 (LDS de-conflict rotation; GEMM unrotates).
// x_in is NOT packed: layer-1 GEMM converts fp32->bf16 in-staging (R3 design).

static __device__ __forceinline__ void pack_w_seg(int lblk, const float* __restrict__ Wl,
                                                  const float* __restrict__ Wr,
                                                  unsigned short* __restrict__ dst,
                                                  int Fout, int Fin, int Kp, int Np) {
  int nb = Kp >> 3;
  int idx = lblk * 256 + threadIdx.x;
  if (idx >= Np * nb) return;
  int row = idx / nb, kb = idx - row * nb;
  int g = kb >> 3, b = kb & 7;
  int dkb = (g << 3) | ((b + row) & 7);
  const float* src = nullptr;
  if (row < Fout)          src = Wl + (size_t)row * Fin;
  else if (row < 2 * Fout) src = Wr + (size_t)(row - Fout) * Fin;
  u16x8 st;
#pragma unroll
  for (int o = 0; o < 8; ++o) {
    int k = kb * 8 + o;
    float v = (src && k < Fin) ? src[k] : 0.f;
    st[o] = f2bf(v);
  }
  *(u16x8*)&dst[(size_t)row * Kp + dkb * 8] = st;
}

#define ADJ_BLK    256   // 65536/256 (first: atomic tail overlaps pack work)
#define PW1_BLK   2660   // 640*1064/256
#define PW2_BLK     60
#define PW3_BLK     24
#define PW4_BLK      8
#define SETUP_BLK (ADJ_BLK + PW1_BLK + PW2_BLK + PW3_BLK + PW4_BLK)

__global__ __launch_bounds__(256) void setup_all(
    const int* __restrict__ esrc, const int* __restrict__ edst,
    const float* __restrict__ W1l, const float* __restrict__ W1r,
    const float* __restrict__ W2l, const float* __restrict__ W2r,
    const float* __restrict__ W3l, const float* __restrict__ W3r,
    const float* __restrict__ W4l, const float* __restrict__ W4r,
    unsigned short* __restrict__ wb1, unsigned short* __restrict__ wb2,
    unsigned short* __restrict__ wb3, unsigned short* __restrict__ wb4,
    int* __restrict__ deg, int* __restrict__ eix) {
  int blk = blockIdx.x;
  if (blk < ADJ_BLK) {
    // padded-adjacency build: deg pre-zeroed by memset before this kernel
    int e = blk * 256 + threadIdx.x;
    int d = edst[e];
    int pos = atomicAdd(&deg[d], 1);
    if (pos < DSTRIDE) eix[(size_t)d * DSTRIDE + pos] = esrc[e];
  } else if (blk < ADJ_BLK + PW1_BLK) {
    pack_w_seg(blk - ADJ_BLK, W1l, W1r, wb1, 320, 8500, 8512, 640);
  } else if (blk < ADJ_BLK + PW1_BLK + PW2_BLK) {
    pack_w_seg(blk - ADJ_BLK - PW1_BLK, W2l, W2r, wb2, 180, 320, 320, 384);
  } else if (blk < ADJ_BLK + PW1_BLK + PW2_BLK + PW3_BLK) {
    pack_w_seg(blk - ADJ_BLK - PW1_BLK - PW2_BLK, W3l, W3r, wb3, 90, 180, 192, 256);
  } else {
    pack_w_seg(blk - ADJ_BLK - PW1_BLK - PW2_BLK - PW3_BLK, W4l, W4r, wb4,
               50, 90, 128, 128);
  }
}

// ======= layer-1 GEMM (R3-proven): A = x_in fp32, cvt in staging ============
// C = A[M,8500->8512] @ B[N,8512]^T, K-split partials over blockIdx.z.
__global__ __launch_bounds__(256) void gemm_f32a(const float* __restrict__ X,
                                                 const unsigned short* __restrict__ B,
                                                 float* __restrict__ C, int N, int M) {
  const int K = 8512, KS = 133, FIN = 8500;
  __shared__ unsigned short smem[3 * 128 * 64];   // As + Bs[2] = 48 KB
  unsigned short* As = smem;

  const int t = threadIdx.x;
  const int bm = blockIdx.x, bn = blockIdx.y;
  const int lane = t & 63;
  const int wave = t >> 6;
  const int wm = (wave & 1) * 64, wn = (wave >> 1) * 64;
  const int l16 = lane & 15, quad = lane >> 4;

  const int gz = (int)gridDim.z, z = (int)blockIdx.z;
  const int per = KS / gz, rem = KS % gz;
  const int k0 = z * per + (z < rem ? z : rem);
  const int k1 = k0 + per + (z < rem ? 1 : 0);

  f32x4 acc[4][4];
#pragma unroll
  for (int i = 0; i < 4; ++i)
#pragma unroll
    for (int j = 0; j < 4; ++j) acc[i][j] = (f32x4){0.f, 0.f, 0.f, 0.f};

  const int srow = t >> 3;          // 0..31
  const int bblk = t & 7;           // 16B block within 64-col group
  const int scol = bblk * 8;
  const float* Xb = X + (size_t)(bm * 128) * FIN;
  const unsigned short* Bbase = B + (size_t)(bn * 128) * K + scol;

  float va[4][8];
  auto loadA = [&](int kt) {
    int gc = kt * 64 + scol;
#pragma unroll
    for (int p = 0; p < 4; ++p) {
      const float* ap = Xb + (size_t)(p * 32 + srow) * FIN + gc;
      if (gc + 8 <= FIN) {
        f32x4 a = *(const f32x4*)ap;
        f32x4 b2 = *(const f32x4*)(ap + 4);
#pragma unroll
        for (int o = 0; o < 4; ++o) { va[p][o] = a[o]; va[p][o + 4] = b2[o]; }
      } else {
#pragma unroll
        for (int o = 0; o < 8; ++o) va[p][o] = (gc + o < FIN) ? ap[o] : 0.f;
      }
    }
  };
  auto writeA = [&]() {
#pragma unroll
    for (int p = 0; p < 4; ++p) {
      int row = p * 32 + srow;
      int rot = ((bblk + row) & 7) * 8;
      bf16x8 bv;
#pragma unroll
      for (int o = 0; o < 8; ++o) bv[o] = (__bf16)va[p][o];
      *(bf16x8*)&As[row * 64 + rot] = bv;
    }
  };
  auto stageB = [&](int kt, int bb) {
    unsigned short* Bd = smem + 128 * 64 + bb * 128 * 64;
#pragma unroll
    for (int p = 0; p < 4; ++p) {
      int row = p * 32 + srow;
      async16(Bbase + (size_t)row * K + kt * 64, &Bd[row * 64 + scol]);
    }
  };

  // prologue: stage k0 (A via regs, B async into buf 0)
  loadA(k0);
  stageB(k0, 0);
  writeA();
  __syncthreads();

  int bb = 0;
  for (int kt = k0; kt < k1; ++kt) {
    bool more = (kt + 1 < k1);
    if (more) {
      loadA(kt + 1);            // global loads in flight under MFMA
      stageB(kt + 1, bb ^ 1);   // async into idle B buffer
    }
    const unsigned short* Bs = smem + 128 * 64 + bb * 128 * 64;
#pragma unroll
    for (int kh = 0; kh < 2; ++kh) {
      const int s8 = ((kh * 4 + quad + l16) & 7) * 8;   // unrotate
      bf16x8 af[4], bfr[4];
#pragma unroll
      for (int i = 0; i < 4; ++i)
        af[i] = *(const bf16x8*)&As[(wm + i * 16 + l16) * 64 + s8];
#pragma unroll
      for (int j = 0; j < 4; ++j)
        bfr[j] = *(const bf16x8*)&Bs[(wn + j * 16 + l16) * 64 + s8];
#pragma unroll
      for (int i = 0; i < 4; ++i)
#pragma unroll
        for (int j = 0; j < 4; ++j)
          acc[i][j] = __builtin_amdgcn_mfma_f32_16x16x32_bf16(af[i], bfr[j], acc[i][j], 0, 0, 0);
    }
    __syncthreads();            // compute done; As reusable
    if (more) {
      writeA();                 // cvt + rotated ds_write (waits va loads)
      __syncthreads();          // staging visible
      bb ^= 1;
    }
  }

  float* Cb = C + (size_t)blockIdx.z * M * N;
#pragma unroll
  for (int i = 0; i < 4; ++i) {
    int rbase = bm * 128 + wm + i * 16 + quad * 4;
#pragma unroll
    for (int j = 0; j < 4; ++j) {
      int col = bn * 128 + wn + j * 16 + l16;
      float* cp = Cb + (size_t)rbase * N + col;
#pragma unroll
      for (int r = 0; r < 4; ++r) cp[(size_t)r * N] = acc[i][j][r];
    }
  }
}

// -------- bf16 MFMA GEMM (layers 2-4): C[bf16] = A[M,K] @ B[N,K]^T ----------
__global__ __launch_bounds__(256) void gemm_bt(const unsigned short* __restrict__ A,
                                               const unsigned short* __restrict__ B,
                                               unsigned short* __restrict__ C, int N,
                                               int K, int M) {
  __shared__ unsigned short smem[2 * 128 * 64];
  unsigned short* As = smem;
  unsigned short* Bs = smem + 128 * 64;

  const int t = threadIdx.x;
  const int bm = blockIdx.x, bn = blockIdx.y;
  const int lane = t & 63;
  const int wave = t >> 6;
  const int wm = (wave & 1) * 64, wn = (wave >> 1) * 64;
  const int l16 = lane & 15, quad = lane >> 4;

  const int ksteps = K >> 6;

  f32x4 acc[4][4];
#pragma unroll
  for (int i = 0; i < 4; ++i)
#pragma unroll
    for (int j = 0; j < 4; ++j) acc[i][j] = (f32x4){0.f, 0.f, 0.f, 0.f};

  const int srow = t >> 3;
  const int scol = (t & 7) * 8;
  const unsigned short* Abase = A + (size_t)(bm * 128) * K + scol;
  const unsigned short* Bbase = B + (size_t)(bn * 128) * K + scol;

  for (int kt = 0; kt < ksteps; ++kt) {
    const unsigned short* Ag = Abase + kt * 64;
    const unsigned short* Bg = Bbase + kt * 64;
#pragma unroll
    for (int p = 0; p < 4; ++p) {
      int row = p * 32 + srow;
      async16(Ag + (size_t)row * K, &As[row * 64 + scol]);
    }
#pragma unroll
    for (int p = 0; p < 4; ++p) {
      int row = p * 32 + srow;
      async16(Bg + (size_t)row * K, &Bs[row * 64 + scol]);
    }
    __syncthreads();
#pragma unroll
    for (int kh = 0; kh < 2; ++kh) {
      const int s8 = ((kh * 4 + quad + l16) & 7) * 8;   // unrotate
      bf16x8 af[4], bfr[4];
#pragma unroll
      for (int i = 0; i < 4; ++i)
        af[i] = *(const bf16x8*)&As[(wm + i * 16 + l16) * 64 + s8];
#pragma unroll
      for (int j = 0; j < 4; ++j)
        bfr[j] = *(const bf16x8*)&Bs[(wn + j * 16 + l16) * 64 + s8];
#pragma unroll
      for (int i = 0; i < 4; ++i)
#pragma unroll
        for (int j = 0; j < 4; ++j)
          acc[i][j] = __builtin_amdgcn_mfma_f32_16x16x32_bf16(af[i], bfr[j], acc[i][j], 0, 0, 0);
    }
    __syncthreads();
  }

#pragma unroll
  for (int i = 0; i < 4; ++i) {
    int rbase = bm * 128 + wm + i * 16 + quad * 4;
#pragma unroll
    for (int j = 0; j < 4; ++j) {
      int col = bn * 128 + wn + j * 16 + l16;
      unsigned short* cp = C + (size_t)rbase * N + col;
#pragma unroll
      for (int r = 0; r < 4; ++r) cp[(size_t)r * N] = f2bf(acc[i][j][r]);
    }
  }
}

// sum nz fp32 K-split slabs -> bf16 y; grid exact NN*640/8/256
__global__ void reduceNbf(const float* __restrict__ yp, unsigned short* __restrict__ y,
                          int nz) {
  int idx = blockIdx.x * 256 + threadIdx.x;    // 8 elems per thread
  const f32x4* p = (const f32x4*)yp;
  const int S = NN * 640 / 4;
  int i2 = idx * 2;
  f32x4 a = p[i2], b = p[i2 + 1];
  for (int sl = 1; sl < nz; ++sl) {
    a += p[i2 + (size_t)sl * S];
    b += p[i2 + 1 + (size_t)sl * S];
  }
  u16x8 st;
#pragma unroll
  for (int o = 0; o < 4; ++o) { st[o] = f2bf(a[o]); st[o + 4] = f2bf(b[o]); }
  *(u16x8*)&y[(size_t)idx * 8] = st;
}

// ---------------- fused mean-aggregate + root + bias + leaky ----------------
// y is bf16 (halved gather traffic). block (64,4): tx = feature quad,
// ty = edge stripe; padded adjacency; in-block loop over feature stripes.
__global__ __launch_bounds__(256) void sage_agg(
    const unsigned short* __restrict__ y, const int* __restrict__ deg,
    const int* __restrict__ eix, const float* __restrict__ bias,
    float* __restrict__ z, int F, int ldy) {
  int i = blockIdx.x;
  int tx = threadIdx.x, ty = threadIdx.y;
  __shared__ int se[DSTRIDE];
  __shared__ float red[3][64][4];
  int d = deg[i]; if (d > DSTRIDE) d = DSTRIDE;
  // stage edge list (d <= 96 -> one pass with 256 threads)
  {
    int lt = ty * 64 + tx;
    if (lt < d) se[lt] = eix[(size_t)i * DSTRIDE + lt];
  }
  __syncthreads();
  int nfb = (F + 255) >> 8;
  for (int fb = 0; fb < nfb; ++fb) {
    int f4 = (fb * 64 + tx) * 4;
    bool active = (f4 < F);
    f32x4 s = {0.f, 0.f, 0.f, 0.f};
    if (active) {
      const unsigned short* yb = y + f4;
      int e = ty;
      for (; e + 4 < d; e += 8) {   // 2x unroll: two independent loads in flight
        u16x4 a = *(const u16x4*)&yb[(size_t)se[e] * ldy];
        u16x4 b = *(const u16x4*)&yb[(size_t)se[e + 4] * ldy];
        s += bf4f(a); s += bf4f(b);
      }
      if (e < d) s += bf4f(*(const u16x4*)&yb[(size_t)se[e] * ldy]);
    }
    if (ty > 0) *(f32x4*)red[ty - 1][tx] = s;
    __syncthreads();
    if (ty == 0 && active) {
      s += *(const f32x4*)red[0][tx];
      s += *(const f32x4*)red[1][tx];
      s += *(const f32x4*)red[2][tx];
      float inv = 1.f / (float)(d > 1 ? d : 1);
      int cnt = F - f4; if (cnt > 4) cnt = 4;
      const unsigned short* yr = &y[(size_t)i * ldy + F + f4];
      float* zo = &z[(size_t)i * F + f4];
      for (int j = 0; j < cnt; ++j) {
        float rv = __uint_as_float(((unsigned)yr[j]) << 16);
        float w = s[j] * inv + rv + bias[f4 + j];
        zo[j] = (w >= 0.f) ? w : LEAKY * w;
      }
    }
    if (fb + 1 < nfb) __syncthreads();   // red reuse barrier
  }
}

// ---------------- batchnorm: row-major partial sums + fused finalize --------
// block-level pre-reduction -> <=8 atomics per address (R10 lesson: chained
// per-address atomics cost ~300ns each; keep chains short).

__global__ __launch_bounds__(256) void bn_part(const float* __restrict__ z,
                                               float* __restrict__ sums, int F) {
  int tx = threadIdx.x, ty = threadIdx.y;      // block (64,4)
  int f = blockIdx.x * 64 + tx;
  float s = 0.f, s2 = 0.f;
  if (f < F) {
    int r0 = blockIdx.y * 512 + ty * 128;
    for (int j = 0; j < 128; ++j) {
      float v = z[(size_t)(r0 + j) * F + f];
      s += v; s2 += v * v;
    }
  }
  __shared__ float ls[4][64], ls2[4][64];
  ls[ty][tx] = s; ls2[ty][tx] = s2;
  __syncthreads();
  if (ty == 0 && f < F) {
    float S  = ls[0][tx] + ls[1][tx] + ls[2][tx] + ls[3][tx];
    float S2 = ls2[0][tx] + ls2[1][tx] + ls2[2][tx] + ls2[3][tx];
    atomicAdd(&sums[f], S);
    atomicAdd(&sums[F + f], S2);
  }
}

// normalize -> next layer's rotated bf16 input (finalizes BN from sums)
__global__ void bn_norm8(const float* __restrict__ z, const float* __restrict__ sums,
                         unsigned short* __restrict__ xout, int F, int Kp) {
  int nb = Kp >> 3;
  int idx = blockIdx.x * 256 + threadIdx.x;    // exact grid
  int row = idx / nb, kb = idx - row * nb;
  int g = kb >> 3, b = kb & 7;
  int dkb = (g << 3) | ((b + row) & 7);
  u16x8 st;
#pragma unroll
  for (int o = 0; o < 8; ++o) {
    int k = kb * 8 + o;
    float v = 0.f;
    if (k < F) {
      float m  = sums[k] * (1.f / NN);
      float var = sums[F + k] * (1.f / NN) - m * m;
      float rs = rsqrtf(var + BN_EPS);
      v = (z[(size_t)row * F + k] - m) * rs;
    }
    st[o] = f2bf(v);
  }
  *(u16x8*)&xout[(size_t)row * Kp + dkb * 8] = st;
}

// ---------------- pool (BN folded in) + 3 FC layers ----------------
// block (64,4): ty stripes the 256 rows of each batch segment.
__global__ void pool_fc(const float* __restrict__ z,  // [4096, 50] pre-BN
                        const float* __restrict__ sums,
                        const float* __restrict__ Wf1, const float* __restrict__ bf1,
                        const float* __restrict__ Wf2, const float* __restrict__ bf2,
                        const float* __restrict__ Wf3, const float* __restrict__ bf3,
                        float* __restrict__ out) {
  __shared__ float ps[4][50];
  __shared__ float pool[50];
  __shared__ float h1[32], h2[16];
  int b = blockIdx.x, tx = threadIdx.x, ty = threadIdx.y;
  if (tx < 50) {
    float s = 0.f;
    int r0 = b * 256 + ty * 64;
    for (int r = 0; r < 64; ++r) s += z[(size_t)(r0 + r) * 50 + tx];
    ps[ty][tx] = s;
  }
  __syncthreads();
  if (ty == 0 && tx < 50) {
    float s = ps[0][tx] + ps[1][tx] + ps[2][tx] + ps[3][tx];
    float m  = sums[tx] * (1.f / NN);
    float var = sums[50 + tx] * (1.f / NN) - m * m;
    float rs = rsqrtf(var + BN_EPS);
    pool[tx] = (s - 256.f * m) * rs;   // sum of normalized = (sum - n*m)*rs
  }
  __syncthreads();
  if (ty == 0 && tx < 32) {
    float s = bf1[tx];
    for (int f = 0; f < 50; ++f) s += pool[f] * Wf1[tx * 50 + f];
    h1[tx] = s;
  }
  __syncthreads();
  if (ty == 0 && tx < 16) {
    float s = bf2[tx];
    for (int f = 0; f < 32; ++f) s += h1[f] * Wf2[tx * 32 + f];
    h2[tx] = s;
  }
  __syncthreads();
  if (ty == 0 && tx == 0) {
    float s = bf3[0];
    for (int f = 0; f < 16; ++f) s += h2[f] * Wf3[f];
    out[b] = s;
  }
}

// ---------------- host ----------------

extern "C" void kernel_launch(void* const* d_in, const int* in_sizes, int n_in,
                              void* d_out, int out_size, void* d_ws, size_t ws_size,
                              hipStream_t stream) {
  const float* x_in = (const float*)d_in[0];
  const int* ei = (const int*)d_in[1];      // int32 per harness contract
  const float* W1l = (const float*)d_in[2];
  const float* b1  = (const float*)d_in[3];
  const float* W1r = (const float*)d_in[4];
  const float* W2l = (const float*)d_in[5];
  const float* b2  = (const float*)d_in[6];
  const float* W2r = (const float*)d_in[7];
  const float* W3l = (const float*)d_in[8];
  const float* b3  = (const float*)d_in[9];
  const float* W3r = (const float*)d_in[10];
  const float* W4l = (const float*)d_in[11];
  const float* b4  = (const float*)d_in[12];
  const float* W4r = (const float*)d_in[13];
  const float* Wf1 = (const float*)d_in[14];
  const float* bf1 = (const float*)d_in[15];
  const float* Wf2 = (const float*)d_in[16];
  const float* bf2 = (const float*)d_in[17];
  const float* Wf3 = (const float*)d_in[18];
  const float* bf3 = (const float*)d_in[19];
  float* out = (float*)d_out;
  (void)in_sizes; (void)n_in; (void)out_size;

  char* ws = (char*)d_ws;
  size_t off = 0;
  auto alloc = [&](size_t bytes) -> void* {
    void* p = ws + off;
    off = (off + bytes + 255) & ~(size_t)255;
    return p;
  };
  unsigned short* xbf = (unsigned short*)alloc((size_t)NN * 320 * 2);  // layers 2-4 A
  unsigned short* wb1 = (unsigned short*)alloc((size_t)640 * 8512 * 2);
  unsigned short* wb2 = (unsigned short*)alloc((size_t)384 * 320 * 2);
  unsigned short* wb3 = (unsigned short*)alloc((size_t)256 * 192 * 2);
  unsigned short* wb4 = (unsigned short*)alloc((size_t)128 * 128 * 2);
  float* z    = (float*)alloc((size_t)NN * 320 * 4);
  // contiguous zero region: deg + bnsum
  int* deg    = (int*)alloc(NN * 4);
  float* bnsum = (float*)alloc(1280 * 4);
  int* eix    = (int*)alloc((size_t)NN * DSTRIDE * 4);
  unsigned short* ybf = (unsigned short*)alloc((size_t)NN * 640 * 2);  // bf16 y
  const size_t YS = (size_t)NN * 640 * 4;   // one fp32 K-split slab
  float* yp = (float*)(ws + off);           // partial slabs last
  int nz = (off + 8 * YS <= ws_size) ? 8 : 4;
  if (off + (size_t)nz * YS > ws_size) return;
  float* bns1 = bnsum;             // 2*320
  float* bns2 = bnsum + 640;       // 2*180
  float* bns3 = bnsum + 1000;      // 2*90
  float* bns4 = bnsum + 1180;      // 2*50

  hipMemsetAsync(deg, 0, NN * 4 + 1280 * 4, stream);

  setup_all<<<dim3(SETUP_BLK), dim3(256), 0, stream>>>(
      ei, ei + NE, W1l, W1r, W2l, W2r, W3l, W3r, W4l, W4r,
      wb1, wb2, wb3, wb4, deg, eix);

  // ---- layer 1: K=8512 (fp32 A in-staging cvt), K-split nz + bf16 reduce ----
  gemm_f32a<<<dim3(32, 5, nz), dim3(256), 0, stream>>>(x_in, wb1, yp, 640, NN);
  reduceNbf<<<dim3(NN * 640 / 8 / 256), dim3(256), 0, stream>>>(yp, ybf, nz);
  sage_agg<<<dim3(NN), dim3(64, 4), 0, stream>>>(ybf, deg, eix, b1, z, 320, 640);
  bn_part<<<dim3(5, 8), dim3(64, 4), 0, stream>>>(z, bns1, 320);
  bn_norm8<<<dim3(NN * 40 / 256), dim3(256), 0, stream>>>(z, bns1, xbf, 320, 320);

  // ---- layer 2: K=320, N=384 ----
  gemm_bt<<<dim3(32, 3, 1), dim3(256), 0, stream>>>(xbf, wb2, ybf, 384, 320, NN);
  sage_agg<<<dim3(NN), dim3(64, 4), 0, stream>>>(ybf, deg, eix, b2, z, 180, 384);
  bn_part<<<dim3(3, 8), dim3(64, 4), 0, stream>>>(z, bns2, 180);
  bn_norm8<<<dim3(NN * 24 / 256), dim3(256), 0, stream>>>(z, bns2, xbf, 180, 192);

  // ---- layer 3: K=192, N=256 ----
  gemm_bt<<<dim3(32, 2, 1), dim3(256), 0, stream>>>(xbf, wb3, ybf, 256, 192, NN);
  sage_agg<<<dim3(NN), dim3(64, 4), 0, stream>>>(ybf, deg, eix, b3, z, 90, 256);
  bn_part<<<dim3(2, 8), dim3(64, 4), 0, stream>>>(z, bns3, 90);
  bn_norm8<<<dim3(NN * 16 / 256), dim3(256), 0, stream>>>(z, bns3, xbf, 90, 128);

  // ---- layer 4: K=128, N=128 ----
  gemm_bt<<<dim3(32, 1, 1), dim3(256), 0, stream>>>(xbf, wb4, ybf, 128, 128, NN);
  sage_agg<<<dim3(NN), dim3(64, 4), 0, stream>>>(ybf, deg, eix, b4, z, 50, 128);
  bn_part<<<dim3(1, 8), dim3(64, 4), 0, stream>>>(z, bns4, 50);

  // ---- pool (BN folded) + FC ----
  pool_fc<<<dim3(16), dim3(64, 4), 0, stream>>>(z, bns4, Wf1, bf1, Wf2, bf2, Wf3, bf3, out);
}

// Round 12
// 465.457 us; speedup vs baseline: 1.5432x; 1.0251x over previous
//
#include <hip/hip_runtime.h>
#include <stdint.h>

#define NN 4096
#define NE 65536
#define LEAKY 0.01f
#define BN_EPS 1e-5f
#define DSTRIDE 96   // padded adjacency stride (mean deg 16, 12+ sigma margin)

typedef float f32x4 __attribute__((ext_vector_type(4)));
typedef __bf16 bf16x8 __attribute__((ext_vector_type(8)));
typedef unsigned short u16x8 __attribute__((ext_vector_type(8)));
typedef unsigned short u16x4 __attribute__((ext_vector_type(4)));

static __device__ __forceinline__ unsigned short f2bf(float v) {
  unsigned int u = __float_as_uint(v);
  u += 0x7fff + ((u >> 16) & 1);   // RNE; inputs are finite
  return (unsigned short)(u >> 16);
}

static __device__ __forceinline__ f32x4 bf4f(u16x4 v) {
  f32x4 r;
#pragma unroll
  for (int j = 0; j < 4; ++j) r[j] = __uint_as_float(((unsigned)v[j]) << 16);
  return r;
}

typedef __attribute__((address_space(1))) void gvoid;
typedef __attribute__((address_space(3))) void lvoid;

static __device__ __forceinline__ void async16(const void* g, void* l) {
  __builtin_amdgcn_global_load_lds((gvoid*)(uintptr_t)g,
                                   (lvoid*)(uint32_t)(uintptr_t)l, 16, 0, 0);
}

// ======================= setup: W packs + adjacency build ===================
// bf16 GEMM-input layout: within each 64-col K-group, row r's 16B block b is
// stored at block (b + r) & 7 (LDS de-conflict rotation; GEMM unrotates).
// x_in is NOT packed: layer-1 GEMM converts fp32->bf16 in-staging (R3 design).

static __device__ __forceinline__ void pack_w_seg(int lblk, const float* __restrict__ Wl,
                                                  const float* __restrict__ Wr,
                                                  unsigned short* __restrict__ dst,
                                                  int Fout, int Fin, int Kp, int Np) {
  int nb = Kp >> 3;
  int idx = lblk * 256 + threadIdx.x;
  if (idx >= Np * nb) return;
  int row = idx / nb, kb = idx - row * nb;
  int g = kb >> 3, b = kb & 7;
  int dkb = (g << 3) | ((b + row) & 7);
  const float* src = nullptr;
  if (row < Fout)          src = Wl + (size_t)row * Fin;
  else if (row < 2 * Fout) src = Wr + (size_t)(row - Fout) * Fin;
  float v[8];
  // vector path when the row stride keeps 16B alignment (Fin%4==0) and the
  // 8-float span is in-bounds; else guarded scalar (W4: Fin=90)
  if (src && ((Fin & 3) == 0) && (kb * 8 + 8 <= Fin)) {
    f32x4 a = *(const f32x4*)(src + kb * 8);
    f32x4 c = *(const f32x4*)(src + kb * 8 + 4);
#pragma unroll
    for (int o = 0; o < 4; ++o) { v[o] = a[o]; v[o + 4] = c[o]; }
  } else {
#pragma unroll
    for (int o = 0; o < 8; ++o) {
      int k = kb * 8 + o;
      v[o] = (src && k < Fin) ? src[k] : 0.f;
    }
  }
  u16x8 st;
#pragma unroll
  for (int o = 0; o < 8; ++o) st[o] = f2bf(v[o]);
  *(u16x8*)&dst[(size_t)row * Kp + dkb * 8] = st;
}

#define ADJ_BLK    256   // 65536/256 (first: atomic tail overlaps pack work)
#define PW1_BLK   2660   // 640*1064/256
#define PW2_BLK     60
#define PW3_BLK     24
#define PW4_BLK      8
#define SETUP_BLK (ADJ_BLK + PW1_BLK + PW2_BLK + PW3_BLK + PW4_BLK)

__global__ __launch_bounds__(256) void setup_all(
    const int* __restrict__ esrc, const int* __restrict__ edst,
    const float* __restrict__ W1l, const float* __restrict__ W1r,
    const float* __restrict__ W2l, const float* __restrict__ W2r,
    const float* __restrict__ W3l, const float* __restrict__ W3r,
    const float* __restrict__ W4l, const float* __restrict__ W4r,
    unsigned short* __restrict__ wb1, unsigned short* __restrict__ wb2,
    unsigned short* __restrict__ wb3, unsigned short* __restrict__ wb4,
    int* __restrict__ deg, int* __restrict__ eix) {
  int blk = blockIdx.x;
  if (blk < ADJ_BLK) {
    // padded-adjacency build: deg pre-zeroed by memset before this kernel
    int e = blk * 256 + threadIdx.x;
    int d = edst[e];
    int pos = atomicAdd(&deg[d], 1);
    if (pos < DSTRIDE) eix[(size_t)d * DSTRIDE + pos] = esrc[e];
  } else if (blk < ADJ_BLK + PW1_BLK) {
    pack_w_seg(blk - ADJ_BLK, W1l, W1r, wb1, 320, 8500, 8512, 640);
  } else if (blk < ADJ_BLK + PW1_BLK + PW2_BLK) {
    pack_w_seg(blk - ADJ_BLK - PW1_BLK, W2l, W2r, wb2, 180, 320, 320, 384);
  } else if (blk < ADJ_BLK + PW1_BLK + PW2_BLK + PW3_BLK) {
    pack_w_seg(blk - ADJ_BLK - PW1_BLK - PW2_BLK, W3l, W3r, wb3, 90, 180, 192, 256);
  } else {
    pack_w_seg(blk - ADJ_BLK - PW1_BLK - PW2_BLK - PW3_BLK, W4l, W4r, wb4,
               50, 90, 128, 128);
  }
}

// ======= layer-1 GEMM (R3-proven): A = x_in fp32, cvt in staging ============
// C = A[M,8500->8512] @ B[N,8512]^T, K-split partials over blockIdx.z (nz=4;
// R11 A/B: nz=8 costs +8us here -- doubled partial traffic beats occupancy).
__global__ __launch_bounds__(256) void gemm_f32a(const float* __restrict__ X,
                                                 const unsigned short* __restrict__ B,
                                                 float* __restrict__ C, int N, int M) {
  const int K = 8512, KS = 133, FIN = 8500;
  __shared__ unsigned short smem[3 * 128 * 64];   // As + Bs[2] = 48 KB
  unsigned short* As = smem;

  const int t = threadIdx.x;
  const int bm = blockIdx.x, bn = blockIdx.y;
  const int lane = t & 63;
  const int wave = t >> 6;
  const int wm = (wave & 1) * 64, wn = (wave >> 1) * 64;
  const int l16 = lane & 15, quad = lane >> 4;

  const int gz = (int)gridDim.z, z = (int)blockIdx.z;
  const int per = KS / gz, rem = KS % gz;
  const int k0 = z * per + (z < rem ? z : rem);
  const int k1 = k0 + per + (z < rem ? 1 : 0);

  f32x4 acc[4][4];
#pragma unroll
  for (int i = 0; i < 4; ++i)
#pragma unroll
    for (int j = 0; j < 4; ++j) acc[i][j] = (f32x4){0.f, 0.f, 0.f, 0.f};

  const int srow = t >> 3;          // 0..31
  const int bblk = t & 7;           // 16B block within 64-col group
  const int scol = bblk * 8;
  const float* Xb = X + (size_t)(bm * 128) * FIN;
  const unsigned short* Bbase = B + (size_t)(bn * 128) * K + scol;

  float va[4][8];
  auto loadA = [&](int kt) {
    int gc = kt * 64 + scol;
#pragma unroll
    for (int p = 0; p < 4; ++p) {
      const float* ap = Xb + (size_t)(p * 32 + srow) * FIN + gc;
      if (gc + 8 <= FIN) {
        f32x4 a = *(const f32x4*)ap;
        f32x4 b2 = *(const f32x4*)(ap + 4);
#pragma unroll
        for (int o = 0; o < 4; ++o) { va[p][o] = a[o]; va[p][o + 4] = b2[o]; }
      } else {
#pragma unroll
        for (int o = 0; o < 8; ++o) va[p][o] = (gc + o < FIN) ? ap[o] : 0.f;
      }
    }
  };
  auto writeA = [&]() {
#pragma unroll
    for (int p = 0; p < 4; ++p) {
      int row = p * 32 + srow;
      int rot = ((bblk + row) & 7) * 8;
      bf16x8 bv;
#pragma unroll
      for (int o = 0; o < 8; ++o) bv[o] = (__bf16)va[p][o];
      *(bf16x8*)&As[row * 64 + rot] = bv;
    }
  };
  auto stageB = [&](int kt, int bb) {
    unsigned short* Bd = smem + 128 * 64 + bb * 128 * 64;
#pragma unroll
    for (int p = 0; p < 4; ++p) {
      int row = p * 32 + srow;
      async16(Bbase + (size_t)row * K + kt * 64, &Bd[row * 64 + scol]);
    }
  };

  // prologue: stage k0 (A via regs, B async into buf 0)
  loadA(k0);
  stageB(k0, 0);
  writeA();
  __syncthreads();

  int bb = 0;
  for (int kt = k0; kt < k1; ++kt) {
    bool more = (kt + 1 < k1);
    if (more) {
      loadA(kt + 1);            // global loads in flight under MFMA
      stageB(kt + 1, bb ^ 1);   // async into idle B buffer
    }
    const unsigned short* Bs = smem + 128 * 64 + bb * 128 * 64;
#pragma unroll
    for (int kh = 0; kh < 2; ++kh) {
      const int s8 = ((kh * 4 + quad + l16) & 7) * 8;   // unrotate
      bf16x8 af[4], bfr[4];
#pragma unroll
      for (int i = 0; i < 4; ++i)
        af[i] = *(const bf16x8*)&As[(wm + i * 16 + l16) * 64 + s8];
#pragma unroll
      for (int j = 0; j < 4; ++j)
        bfr[j] = *(const bf16x8*)&Bs[(wn + j * 16 + l16) * 64 + s8];
#pragma unroll
      for (int i = 0; i < 4; ++i)
#pragma unroll
        for (int j = 0; j < 4; ++j)
          acc[i][j] = __builtin_amdgcn_mfma_f32_16x16x32_bf16(af[i], bfr[j], acc[i][j], 0, 0, 0);
    }
    __syncthreads();            // compute done; As reusable
    if (more) {
      writeA();                 // cvt + rotated ds_write (waits va loads)
      __syncthreads();          // staging visible
      bb ^= 1;
    }
  }

  float* Cb = C + (size_t)blockIdx.z * M * N;
#pragma unroll
  for (int i = 0; i < 4; ++i) {
    int rbase = bm * 128 + wm + i * 16 + quad * 4;
#pragma unroll
    for (int j = 0; j < 4; ++j) {
      int col = bn * 128 + wn + j * 16 + l16;
      float* cp = Cb + (size_t)rbase * N + col;
#pragma unroll
      for (int r = 0; r < 4; ++r) cp[(size_t)r * N] = acc[i][j][r];
    }
  }
}

// -------- bf16 MFMA GEMM (layers 2-4): C[bf16] = A[M,K] @ B[N,K]^T ----------
__global__ __launch_bounds__(256) void gemm_bt(const unsigned short* __restrict__ A,
                                               const unsigned short* __restrict__ B,
                                               unsigned short* __restrict__ C, int N,
                                               int K, int M) {
  __shared__ unsigned short smem[2 * 128 * 64];
  unsigned short* As = smem;
  unsigned short* Bs = smem + 128 * 64;

  const int t = threadIdx.x;
  const int bm = blockIdx.x, bn = blockIdx.y;
  const int lane = t & 63;
  const int wave = t >> 6;
  const int wm = (wave & 1) * 64, wn = (wave >> 1) * 64;
  const int l16 = lane & 15, quad = lane >> 4;

  const int ksteps = K >> 6;

  f32x4 acc[4][4];
#pragma unroll
  for (int i = 0; i < 4; ++i)
#pragma unroll
    for (int j = 0; j < 4; ++j) acc[i][j] = (f32x4){0.f, 0.f, 0.f, 0.f};

  const int srow = t >> 3;
  const int scol = (t & 7) * 8;
  const unsigned short* Abase = A + (size_t)(bm * 128) * K + scol;
  const unsigned short* Bbase = B + (size_t)(bn * 128) * K + scol;

  for (int kt = 0; kt < ksteps; ++kt) {
    const unsigned short* Ag = Abase + kt * 64;
    const unsigned short* Bg = Bbase + kt * 64;
#pragma unroll
    for (int p = 0; p < 4; ++p) {
      int row = p * 32 + srow;
      async16(Ag + (size_t)row * K, &As[row * 64 + scol]);
    }
#pragma unroll
    for (int p = 0; p < 4; ++p) {
      int row = p * 32 + srow;
      async16(Bg + (size_t)row * K, &Bs[row * 64 + scol]);
    }
    __syncthreads();
#pragma unroll
    for (int kh = 0; kh < 2; ++kh) {
      const int s8 = ((kh * 4 + quad + l16) & 7) * 8;   // unrotate
      bf16x8 af[4], bfr[4];
#pragma unroll
      for (int i = 0; i < 4; ++i)
        af[i] = *(const bf16x8*)&As[(wm + i * 16 + l16) * 64 + s8];
#pragma unroll
      for (int j = 0; j < 4; ++j)
        bfr[j] = *(const bf16x8*)&Bs[(wn + j * 16 + l16) * 64 + s8];
#pragma unroll
      for (int i = 0; i < 4; ++i)
#pragma unroll
        for (int j = 0; j < 4; ++j)
          acc[i][j] = __builtin_amdgcn_mfma_f32_16x16x32_bf16(af[i], bfr[j], acc[i][j], 0, 0, 0);
    }
    __syncthreads();
  }

#pragma unroll
  for (int i = 0; i < 4; ++i) {
    int rbase = bm * 128 + wm + i * 16 + quad * 4;
#pragma unroll
    for (int j = 0; j < 4; ++j) {
      int col = bn * 128 + wn + j * 16 + l16;
      unsigned short* cp = C + (size_t)rbase * N + col;
#pragma unroll
      for (int r = 0; r < 4; ++r) cp[(size_t)r * N] = f2bf(acc[i][j][r]);
    }
  }
}

// sum nz fp32 K-split slabs -> bf16 y; grid exact NN*640/8/256
__global__ void reduceNbf(const float* __restrict__ yp, unsigned short* __restrict__ y,
                          int nz) {
  int idx = blockIdx.x * 256 + threadIdx.x;    // 8 elems per thread
  const f32x4* p = (const f32x4*)yp;
  const int S = NN * 640 / 4;
  int i2 = idx * 2;
  f32x4 a = p[i2], b = p[i2 + 1];
  for (int sl = 1; sl < nz; ++sl) {
    a += p[i2 + (size_t)sl * S];
    b += p[i2 + 1 + (size_t)sl * S];
  }
  u16x8 st;
#pragma unroll
  for (int o = 0; o < 4; ++o) { st[o] = f2bf(a[o]); st[o + 4] = f2bf(b[o]); }
  *(u16x8*)&y[(size_t)idx * 8] = st;
}

// ---------------- fused mean-aggregate + root + bias + leaky ----------------
// y is bf16 (halved gather traffic). block (64,4): tx = feature quad,
// ty = edge stripe; padded adjacency; in-block loop over feature stripes.
__global__ __launch_bounds__(256) void sage_agg(
    const unsigned short* __restrict__ y, const int* __restrict__ deg,
    const int* __restrict__ eix, const float* __restrict__ bias,
    float* __restrict__ z, int F, int ldy) {
  int i = blockIdx.x;
  int tx = threadIdx.x, ty = threadIdx.y;
  __shared__ int se[DSTRIDE];
  __shared__ float red[3][64][4];
  int d = deg[i]; if (d > DSTRIDE) d = DSTRIDE;
  // stage edge list (d <= 96 -> one pass with 256 threads)
  {
    int lt = ty * 64 + tx;
    if (lt < d) se[lt] = eix[(size_t)i * DSTRIDE + lt];
  }
  __syncthreads();
  int nfb = (F + 255) >> 8;
  for (int fb = 0; fb < nfb; ++fb) {
    int f4 = (fb * 64 + tx) * 4;
    bool active = (f4 < F);
    f32x4 s = {0.f, 0.f, 0.f, 0.f};
    if (active) {
      const unsigned short* yb = y + f4;
      int e = ty;
      for (; e + 4 < d; e += 8) {   // 2x unroll: two independent loads in flight
        u16x4 a = *(const u16x4*)&yb[(size_t)se[e] * ldy];
        u16x4 b = *(const u16x4*)&yb[(size_t)se[e + 4] * ldy];
        s += bf4f(a); s += bf4f(b);
      }
      if (e < d) s += bf4f(*(const u16x4*)&yb[(size_t)se[e] * ldy]);
    }
    if (ty > 0) *(f32x4*)red[ty - 1][tx] = s;
    __syncthreads();
    if (ty == 0 && active) {
      s += *(const f32x4*)red[0][tx];
      s += *(const f32x4*)red[1][tx];
      s += *(const f32x4*)red[2][tx];
      float inv = 1.f / (float)(d > 1 ? d : 1);
      int cnt = F - f4; if (cnt > 4) cnt = 4;
      const unsigned short* yr = &y[(size_t)i * ldy + F + f4];
      float* zo = &z[(size_t)i * F + f4];
      for (int j = 0; j < cnt; ++j) {
        float rv = __uint_as_float(((unsigned)yr[j]) << 16);
        float w = s[j] * inv + rv + bias[f4 + j];
        zo[j] = (w >= 0.f) ? w : LEAKY * w;
      }
    }
    if (fb + 1 < nfb) __syncthreads();   // red reuse barrier
  }
}

// ---------------- batchnorm: row-major partial sums + fused finalize --------
// block-level pre-reduction -> <=8 atomics per address (R10 lesson: chained
// per-address atomics cost ~300ns each; keep chains short).

__global__ __launch_bounds__(256) void bn_part(const float* __restrict__ z,
                                               float* __restrict__ sums, int F) {
  int tx = threadIdx.x, ty = threadIdx.y;      // block (64,4)
  int f = blockIdx.x * 64 + tx;
  float s = 0.f, s2 = 0.f;
  if (f < F) {
    int r0 = blockIdx.y * 512 + ty * 128;
    for (int j = 0; j < 128; ++j) {
      float v = z[(size_t)(r0 + j) * F + f];
      s += v; s2 += v * v;
    }
  }
  __shared__ float ls[4][64], ls2[4][64];
  ls[ty][tx] = s; ls2[ty][tx] = s2;
  __syncthreads();
  if (ty == 0 && f < F) {
    float S  = ls[0][tx] + ls[1][tx] + ls[2][tx] + ls[3][tx];
    float S2 = ls2[0][tx] + ls2[1][tx] + ls2[2][tx] + ls2[3][tx];
    atomicAdd(&sums[f], S);
    atomicAdd(&sums[F + f], S2);
  }
}

// normalize -> next layer's rotated bf16 input (finalizes BN from sums)
__global__ void bn_norm8(const float* __restrict__ z, const float* __restrict__ sums,
                         unsigned short* __restrict__ xout, int F, int Kp) {
  int nb = Kp >> 3;
  int idx = blockIdx.x * 256 + threadIdx.x;    // exact grid
  int row = idx / nb, kb = idx - row * nb;
  int g = kb >> 3, b = kb & 7;
  int dkb = (g << 3) | ((b + row) & 7);
  u16x8 st;
#pragma unroll
  for (int o = 0; o < 8; ++o) {
    int k = kb * 8 + o;
    float v = 0.f;
    if (k < F) {
      float m  = sums[k] * (1.f / NN);
      float var = sums[F + k] * (1.f / NN) - m * m;
      float rs = rsqrtf(var + BN_EPS);
      v = (z[(size_t)row * F + k] - m) * rs;
    }
    st[o] = f2bf(v);
  }
  *(u16x8*)&xout[(size_t)row * Kp + dkb * 8] = st;
}

// ---------------- pool (BN folded in) + 3 FC layers ----------------
// block (64,4): ty stripes the 256 rows of each batch segment.
__global__ void pool_fc(const float* __restrict__ z,  // [4096, 50] pre-BN
                        const float* __restrict__ sums,
                        const float* __restrict__ Wf1, const float* __restrict__ bf1,
                        const float* __restrict__ Wf2, const float* __restrict__ bf2,
                        const float* __restrict__ Wf3, const float* __restrict__ bf3,
                        float* __restrict__ out) {
  __shared__ float ps[4][50];
  __shared__ float pool[50];
  __shared__ float h1[32], h2[16];
  int b = blockIdx.x, tx = threadIdx.x, ty = threadIdx.y;
  if (tx < 50) {
    float s = 0.f;
    int r0 = b * 256 + ty * 64;
    for (int r = 0; r < 64; ++r) s += z[(size_t)(r0 + r) * 50 + tx];
    ps[ty][tx] = s;
  }
  __syncthreads();
  if (ty == 0 && tx < 50) {
    float s = ps[0][tx] + ps[1][tx] + ps[2][tx] + ps[3][tx];
    float m  = sums[tx] * (1.f / NN);
    float var = sums[50 + tx] * (1.f / NN) - m * m;
    float rs = rsqrtf(var + BN_EPS);
    pool[tx] = (s - 256.f * m) * rs;   // sum of normalized = (sum - n*m)*rs
  }
  __syncthreads();
  if (ty == 0 && tx < 32) {
    float s = bf1[tx];
    for (int f = 0; f < 50; ++f) s += pool[f] * Wf1[tx * 50 + f];
    h1[tx] = s;
  }
  __syncthreads();
  if (ty == 0 && tx < 16) {
    float s = bf2[tx];
    for (int f = 0; f < 32; ++f) s += h1[f] * Wf2[tx * 32 + f];
    h2[tx] = s;
  }
  __syncthreads();
  if (ty == 0 && tx == 0) {
    float s = bf3[0];
    for (int f = 0; f < 16; ++f) s += h2[f] * Wf3[f];
    out[b] = s;
  }
}

// ---------------- host ----------------

extern "C" void kernel_launch(void* const* d_in, const int* in_sizes, int n_in,
                              void* d_out, int out_size, void* d_ws, size_t ws_size,
                              hipStream_t stream) {
  const float* x_in = (const float*)d_in[0];
  const int* ei = (const int*)d_in[1];      // int32 per harness contract
  const float* W1l = (const float*)d_in[2];
  const float* b1  = (const float*)d_in[3];
  const float* W1r = (const float*)d_in[4];
  const float* W2l = (const float*)d_in[5];
  const float* b2  = (const float*)d_in[6];
  const float* W2r = (const float*)d_in[7];
  const float* W3l = (const float*)d_in[8];
  const float* b3  = (const float*)d_in[9];
  const float* W3r = (const float*)d_in[10];
  const float* W4l = (const float*)d_in[11];
  const float* b4  = (const float*)d_in[12];
  const float* W4r = (const float*)d_in[13];
  const float* Wf1 = (const float*)d_in[14];
  const float* bf1 = (const float*)d_in[15];
  const float* Wf2 = (const float*)d_in[16];
  const float* bf2 = (const float*)d_in[17];
  const float* Wf3 = (const float*)d_in[18];
  const float* bf3 = (const float*)d_in[19];
  float* out = (float*)d_out;
  (void)in_sizes; (void)n_in; (void)out_size;

  char* ws = (char*)d_ws;
  size_t off = 0;
  auto alloc = [&](size_t bytes) -> void* {
    void* p = ws + off;
    off = (off + bytes + 255) & ~(size_t)255;
    return p;
  };
  unsigned short* xbf = (unsigned short*)alloc((size_t)NN * 320 * 2);  // layers 2-4 A
  unsigned short* wb1 = (unsigned short*)alloc((size_t)640 * 8512 * 2);
  unsigned short* wb2 = (unsigned short*)alloc((size_t)384 * 320 * 2);
  unsigned short* wb3 = (unsigned short*)alloc((size_t)256 * 192 * 2);
  unsigned short* wb4 = (unsigned short*)alloc((size_t)128 * 128 * 2);
  float* z    = (float*)alloc((size_t)NN * 320 * 4);
  // contiguous zero region: deg + bnsum
  int* deg    = (int*)alloc(NN * 4);
  float* bnsum = (float*)alloc(1280 * 4);
  int* eix    = (int*)alloc((size_t)NN * DSTRIDE * 4);
  unsigned short* ybf = (unsigned short*)alloc((size_t)NN * 640 * 2);  // bf16 y
  const size_t YS = (size_t)NN * 640 * 4;   // one fp32 K-split slab
  float* yp = (float*)(ws + off);           // partial slabs last
  const int nz = 4;                         // R11 A/B: nz=8 regressed gemm +8us
  if (off + (size_t)nz * YS > ws_size) return;
  float* bns1 = bnsum;             // 2*320
  float* bns2 = bnsum + 640;       // 2*180
  float* bns3 = bnsum + 1000;      // 2*90
  float* bns4 = bnsum + 1180;      // 2*50

  hipMemsetAsync(deg, 0, NN * 4 + 1280 * 4, stream);

  setup_all<<<dim3(SETUP_BLK), dim3(256), 0, stream>>>(
      ei, ei + NE, W1l, W1r, W2l, W2r, W3l, W3r, W4l, W4r,
      wb1, wb2, wb3, wb4, deg, eix);

  // ---- layer 1: K=8512 (fp32 A in-staging cvt), K-split nz=4 + bf16 reduce ----
  gemm_f32a<<<dim3(32, 5, nz), dim3(256), 0, stream>>>(x_in, wb1, yp, 640, NN);
  reduceNbf<<<dim3(NN * 640 / 8 / 256), dim3(256), 0, stream>>>(yp, ybf, nz);
  sage_agg<<<dim3(NN), dim3(64, 4), 0, stream>>>(ybf, deg, eix, b1, z, 320, 640);
  bn_part<<<dim3(5, 8), dim3(64, 4), 0, stream>>>(z, bns1, 320);
  bn_norm8<<<dim3(NN * 40 / 256), dim3(256), 0, stream>>>(z, bns1, xbf, 320, 320);

  // ---- layer 2: K=320, N=384 ----
  gemm_bt<<<dim3(32, 3, 1), dim3(256), 0, stream>>>(xbf, wb2, ybf, 384, 320, NN);
  sage_agg<<<dim3(NN), dim3(64, 4), 0, stream>>>(ybf, deg, eix, b2, z, 180, 384);
  bn_part<<<dim3(3, 8), dim3(64, 4), 0, stream>>>(z, bns2, 180);
  bn_norm8<<<dim3(NN * 24 / 256), dim3(256), 0, stream>>>(z, bns2, xbf, 180, 192);

  // ---- layer 3: K=192, N=256 ----
  gemm_bt<<<dim3(32, 2, 1), dim3(256), 0, stream>>>(xbf, wb3, ybf, 256, 192, NN);
  sage_agg<<<dim3(NN), dim3(64, 4), 0, stream>>>(ybf, deg, eix, b3, z, 90, 256);
  bn_part<<<dim3(2, 8), dim3(64, 4), 0, stream>>>(z, bns3, 90);
  bn_norm8<<<dim3(NN * 16 / 256), dim3(256), 0, stream>>>(z, bns3, xbf, 90, 128);

  // ---- layer 4: K=128, N=128 ----
  gemm_bt<<<dim3(32, 1, 1), dim3(256), 0, stream>>>(xbf, wb4, ybf, 128, 128, NN);
  sage_agg<<<dim3(NN), dim3(64, 4), 0, stream>>>(ybf, deg, eix, b4, z, 50, 128);
  bn_part<<<dim3(1, 8), dim3(64, 4), 0, stream>>>(z, bns4, 50);

  // ---- pool (BN folded) + FC ----
  pool_fc<<<dim3(16), dim3(64, 4), 0, stream>>>(z, bns4, Wf1, bf1, Wf2, bf2, Wf3, bf3, out);
}